// Round 2
// baseline (275.168 us; speedup 1.0000x reference)
//
#include <hip/hip_runtime.h>
#include <hip/hip_bf16.h>
#include <stdint.h>
#include <stddef.h>

#define HH_EPS 1e-8f

typedef __attribute__((ext_vector_type(8))) short short8;
typedef __attribute__((ext_vector_type(4))) float f32x4;

#define CDIM 512
#define SDIM 4096
#define BN 128        // spatial columns per block (was 64)
#define BK 32
#define NSTEP 16      // CDIM / BK

// ---------------------------------------------------------------------------
// Frag-tiled W for B-operand consumption (o = MFMA col, k = reduction):
//   element (o,c) lives at frag [kt=c>>5][ow=o>>7][oi=(o>>4)&7],
//   lane = ((c>>3)&3)*16 + (o&15), elem = c&7.
// Each fragment is 64 lanes x 16 B = 1 KB, contiguous, in exact lane-consume
// order -> global_load_lds-able and conflict-free ds_read_b128.
// ---------------------------------------------------------------------------
__device__ __forceinline__ size_t wt_idx(int o, int c) {
    return ((((size_t)(c >> 5) * 4 + (o >> 7)) * 8 + ((o >> 4) & 7)) * 64
            + (size_t)((c >> 3) & 3) * 16 + (o & 15)) * 8 + (c & 7);
}

// ---------------------------------------------------------------------------
// Kernel 1: W = H_32 ... H_1, column-parallel, on-the-fly normalization.
// ---------------------------------------------------------------------------
__global__ void compute_w(const float* __restrict__ V,
                          __hip_bfloat16* __restrict__ Wt) {
    const int wave = threadIdx.x >> 6;
    const int lane = threadIdx.x & 63;
    const int jA = (blockIdx.x * 4 + wave) * 2;
    const int jB = jA + 1;
    const int ib = lane * 8;

    float wA[8], wB[8];
    #pragma unroll
    for (int r = 0; r < 8; r++) {
        wA[r] = (ib + r == jA) ? 1.0f : 0.0f;
        wB[r] = (ib + r == jB) ? 1.0f : 0.0f;
    }
    float4 c0 = *(const float4*)(V + ib);
    float4 c1 = *(const float4*)(V + ib + 4);

    for (int k = 0; k < 32; k++) {
        const float v[8] = {c0.x, c0.y, c0.z, c0.w, c1.x, c1.y, c1.z, c1.w};
        if (k < 31) {
            c0 = *(const float4*)(V + (size_t)(k + 1) * 512 + ib);
            c1 = *(const float4*)(V + (size_t)(k + 1) * 512 + ib + 4);
        }
        float dA = 0.0f, dB = 0.0f, ss = 0.0f;
        #pragma unroll
        for (int r = 0; r < 8; r++) {
            dA += v[r] * wA[r];
            dB += v[r] * wB[r];
            ss += v[r] * v[r];
        }
        #pragma unroll
        for (int off = 32; off > 0; off >>= 1) {
            dA += __shfl_xor(dA, off);
            dB += __shfl_xor(dB, off);
            ss += __shfl_xor(ss, off);
        }
        const float t = sqrtf(ss) + HH_EPS;
        const float scale = 2.0f / (t * t);
        const float tA = scale * dA, tB = scale * dB;
        #pragma unroll
        for (int r = 0; r < 8; r++) {
            wA[r] -= tA * v[r];
            wB[r] -= tB * v[r];
        }
    }
    #pragma unroll
    for (int r = 0; r < 8; r++) {
        Wt[wt_idx(ib + r, jA)] = __float2bfloat16(wA[r]);
        Wt[wt_idx(ib + r, jB)] = __float2bfloat16(wB[r]);
    }
}

// ---------------------------------------------------------------------------
// Async / sync primitives
// ---------------------------------------------------------------------------
__device__ __forceinline__ void gld_lds16(const void* g, void* l) {
    __builtin_amdgcn_global_load_lds(
        (const __attribute__((address_space(1))) uint32_t*)g,
        (__attribute__((address_space(3))) uint32_t*)l, 16, 0, 0);
}

template<int N> __device__ __forceinline__ void wait_vm() {
    // gfx9 s_waitcnt imm: vmcnt[3:0]=b3:0, vmcnt[5:4]=b15:14, exp=b6:4, lgkm=b11:8
    __builtin_amdgcn_s_waitcnt((N & 15) | ((N >> 4) << 14) | (7 << 4) | (15 << 8));
}

__device__ __forceinline__ void lds_barrier() {
    // lgkmcnt(0) only: my LDS ops visible; counted global loads stay in flight.
    __builtin_amdgcn_s_waitcnt(0xC07F);
    __builtin_amdgcn_s_barrier();
}

// Pre-barrier vm target at step kt: keep only B(kt+4) in flight (8 loads);
// retires A(kt+1) (own 4 DMAs -> partner-visible after barrier) and B(kt+3).
constexpr int vm_pre(int kt) { return (kt + 4 < NSTEP) ? 8 : 0; }

// ---------------------------------------------------------------------------
// Kernel 2: out[b] = W @ x[b].  BM=512 (all o), BN=128, BK=32.
// 512 thr / 8 waves: wave(ow=w&3, nh=w>>2) owns o-range ow*128, n-half nh*64.
// MFMA operands SWAPPED vs v0: A = x frags (m = spatial), B = W frags (n = o)
//   -> D reg axis is contiguous spatial -> float4 epilogue stores.
//   A(W): per-wave 4x global_load_lds (frag-linear), dbuf, dist-1, L2-hot.
//   B(x): fp32 gather -> 4-deep reg stages (dist-4) -> cvt -> frag-ordered LDS
//        (all ds_read_b128 are contiguous 1 KB wave reads -> 0 bank conflicts).
//   Sync: counted pre-barrier vmcnt(8) -> next x-tile rides across barriers.
// ---------------------------------------------------------------------------
__global__ __launch_bounds__(512, 2) void hh_gemm(
    const float* __restrict__ x,
    const __hip_bfloat16* __restrict__ Wt,
    float* __restrict__ out)
{
    __shared__ __attribute__((aligned(16))) __hip_bfloat16 Albuf[2][CDIM * BK]; // 2 x 32 KB (W)
    __shared__ __attribute__((aligned(16))) __hip_bfloat16 Bbuf[2][BN * BK];    // 2 x 8 KB  (x)

    const int tid  = threadIdx.x;
    const int wave = tid >> 6, lane = tid & 63;
    const int ow = wave & 3, nh = wave >> 2;
    const int quad = lane >> 4, l16 = lane & 15;

    const int bid = blockIdx.x;          // 0..511
    const int b   = bid >> 5;            // 0..15
    const int nt  = bid & 31;            // 0..31
    const int n0  = nt * BN;

    const float* xb = x + (size_t)b * CDIM * SDIM;
    const int bn = tid & 127;            // n owned for x staging
    const int kq = tid >> 7;             // k-octet owned for x staging (0..3)
    const float* xp0 = xb + (size_t)(kq * 8) * SDIM + n0 + bn;

    f32x4 acc[4][8];                     // [mi = n-frag][oi = o-frag]
    #pragma unroll
    for (int mi = 0; mi < 4; mi++)
        #pragma unroll
        for (int oi = 0; oi < 8; oi++) {
            f32x4 z = {0.0f, 0.0f, 0.0f, 0.0f};
            acc[mi][oi] = z;
        }

    float pfB[4][8];

    auto loadA = [&](int kt, int p) {    // each wave stages its own 4 KB half
        const char* gbase = (const char*)Wt
            + ((size_t)(kt * 4 + ow) * 8 + nh * 4) * 1024 + (size_t)lane * 16;
        char* lbase = (char*)&Albuf[p][0] + (size_t)(ow * 8 + nh * 4) * 1024;
        #pragma unroll
        for (int i = 0; i < 4; i++)
            gld_lds16(gbase + (size_t)i * 1024, lbase + (size_t)i * 1024);
    };
    auto loadB = [&](int kt, float* dst) {
        const float* p = xp0 + (size_t)kt * BK * SDIM;
        #pragma unroll
        for (int j = 0; j < 8; j++)
            dst[j] = __builtin_nontemporal_load(p + (size_t)j * SDIM);
    };
    auto writeB = [&](int buf, const float* src) {
        short8 pk;
        #pragma unroll
        for (int j = 0; j < 8; j++) {
            __hip_bfloat16 h = __float2bfloat16(src[j]);
            pk[j] = *(short*)&h;
        }
        // frag-ordered: chunk (bn>>4), lane = kq*16 + (bn&15), 8 elems
        *(short8*)(&Bbuf[buf][(size_t)(((bn >> 4) * 4 + kq) * 16 + (bn & 15)) * 8]) = pk;
    };

    // ---- prologue: A(0)->LDS0, B(0..3)->regs, B(0)->LDS0 ----
    loadA(0, 0);
    loadB(0, pfB[0]);
    loadB(1, pfB[1]);
    loadB(2, pfB[2]);
    loadB(3, pfB[3]);
    writeB(0, pfB[0]);    // compiler vmcnt wait retires A(0),B(0); B(1..3) fly
    wait_vm<24>();        // (no-op in practice; pins A(0) retired pre-barrier)
    lds_barrier();

#define DO_STEP(KT)                                                            \
    {                                                                          \
        constexpr int p = (KT) & 1;                                            \
        if constexpr ((KT) + 1 < NSTEP) loadA((KT) + 1, p ^ 1);                \
        if constexpr ((KT) + 4 < NSTEP) loadB((KT) + 4, pfB[(KT) % 4]);        \
        short8 afr[4], bfr[8];                                                 \
        _Pragma("unroll")                                                      \
        for (int mi = 0; mi < 4; mi++)                                         \
            afr[mi] = *(const short8*)(&Bbuf[p][(size_t)((nh * 4 + mi) * 64    \
                                                         + lane) * 8]);       \
        _Pragma("unroll")                                                      \
        for (int oi = 0; oi < 8; oi++)                                         \
            bfr[oi] = *(const short8*)(&Albuf[p][(size_t)((ow * 8 + oi) * 64   \
                                                          + lane) * 8]);      \
        _Pragma("unroll")                                                      \
        for (int mi = 0; mi < 4; mi++)                                         \
            _Pragma("unroll")                                                  \
            for (int oi = 0; oi < 8; oi++)                                     \
                acc[mi][oi] = __builtin_amdgcn_mfma_f32_16x16x32_bf16(         \
                    afr[mi], bfr[oi], acc[mi][oi], 0, 0, 0);                   \
        if constexpr ((KT) + 1 < NSTEP) {                                      \
            writeB(p ^ 1, pfB[((KT) + 1) % 4]);                                \
            wait_vm<vm_pre(KT)>();  /* own A(kt+1)+B(kt+3) landed; B(kt+4) */  \
            lds_barrier();          /* flies on across the barrier */          \
        }                                                                      \
    }

    DO_STEP(0)  DO_STEP(1)  DO_STEP(2)  DO_STEP(3)
    DO_STEP(4)  DO_STEP(5)  DO_STEP(6)  DO_STEP(7)
    DO_STEP(8)  DO_STEP(9)  DO_STEP(10) DO_STEP(11)
    DO_STEP(12) DO_STEP(13) DO_STEP(14) DO_STEP(15)
#undef DO_STEP

    // ---- epilogue: D row (reg axis) = spatial n -> contiguous float4 ----
    float* ob = out + (size_t)b * CDIM * SDIM + n0 + nh * 64;
    #pragma unroll
    for (int oi = 0; oi < 8; oi++) {
        const int o = ow * 128 + oi * 16 + l16;
        #pragma unroll
        for (int mi = 0; mi < 4; mi++) {
            f32x4* dst = (f32x4*)(ob + (size_t)o * SDIM + mi * 16 + quad * 4);
            __builtin_nontemporal_store(acc[mi][oi], dst);
        }
    }
}

// ---------------------------------------------------------------------------
extern "C" void kernel_launch(void* const* d_in, const int* in_sizes, int n_in,
                              void* d_out, int out_size, void* d_ws, size_t ws_size,
                              hipStream_t stream) {
    const float* x = (const float*)d_in[0];   // [16, 512, 64, 64]
    const float* V = (const float*)d_in[1];   // [32, 512]
    float* out = (float*)d_out;               // [16, 512, 64, 64] fp32

    __hip_bfloat16* Wt = (__hip_bfloat16*)d_ws;   // 512 KB frag-tiled W

    compute_w<<<64, 256, 0, stream>>>(V, Wt);
    hh_gemm<<<512, 512, 0, stream>>>(x, Wt, out);
}